// Round 1
// baseline (523.416 us; speedup 1.0000x reference)
//
#include <hip/hip_runtime.h>
#include <cstdint>

typedef unsigned long long u64;

constexpr int B = 4096;
constexpr int D = 8192;
constexpr int H = 4096;
constexpr int L = 128;
constexpr int DW = D / 64;   // 128 u64 words along d
constexpr int HW = H / 64;   // 64 u64 words along h

// ---------------- packing kernels ----------------

// Pack x[B][D] (values exactly 0.0/1.0) into xp[B][DW], row-major.
// One wave packs one aligned 64-element chunk via ballot; reads fully coalesced.
__global__ __launch_bounds__(256) void k_pack_x(const float* __restrict__ x,
                                                u64* __restrict__ xp) {
    int i = blockIdx.x * 256 + threadIdx.x;          // element index
    int lane = threadIdx.x & 63;
    float v = x[i];
    u64 m = __ballot(v > 0.5f);
    if (lane == 0) xp[i >> 6] = m;
}

// Pack wb = (enc_weight > 0.5) into word-major layout wbpw[w][H] (w = d-word).
// This layout makes k_z's per-lane loads (consecutive h, same w) coalesced.
__global__ __launch_bounds__(256) void k_pack_wb(const float* __restrict__ e,
                                                 u64* __restrict__ wbpw) {
    int i = blockIdx.x * 256 + threadIdx.x;          // element index in [0, H*D)
    int lane = threadIdx.x & 63;
    float v = e[i];
    u64 m = __ballot(v > 0.5f);
    if (lane == 0) {
        int h = i >> 13;             // D = 8192 = 2^13
        int w = (i & (D - 1)) >> 6;  // d-word index
        wbpw[(size_t)w * H + h] = m;
    }
}

// Bit-transpose wbpw -> wbtp[d][HW] (bit j of word wh = wb[wh*64+j][d]).
// One wave handles (dblock, wh): lane j reads the word for row wh*64+j
// (coalesced), then 64 ballots produce the 64 transposed words.
__global__ __launch_bounds__(256) void k_build_wbt(const u64* __restrict__ wbpw,
                                                   u64* __restrict__ wbtp) {
    int wid = (blockIdx.x * 256 + threadIdx.x) >> 6; // wave id
    int lane = threadIdx.x & 63;
    int dblock = wid >> 6;    // [0, DW)
    int wh = wid & (HW - 1);  // [0, HW)
    u64 Wj = wbpw[(size_t)dblock * H + wh * 64 + lane];
    u64 myword = 0;
    #pragma unroll 1
    for (int jj = 0; jj < 64; ++jj) {
        u64 m = __ballot((int)((Wj >> jj) & 1ull));
        if (lane == jj) myword = m;
    }
    wbtp[(size_t)(dblock * 64 + lane) * HW + wh] = myword;
}

// ---------------- tiny precompute kernels ----------------

// Column sums of wb and the broadcast output row pattern.
__global__ void k_base(const u64* __restrict__ wbtp, const float* __restrict__ bias3,
                       float* __restrict__ base) {
    int d = blockIdx.x * blockDim.x + threadIdx.x;
    int s = 0;
    for (int w = 0; w < HW; ++w) s += (int)__popcll(wbtp[(size_t)d * HW + w]);
    base[d] = ((float)s + bias3[d] > 1.0f) ? 1.0f : 0.0f;
}

// Minimal integer count c such that (float)c + bias0[h] > 1.0f (exact fp32 semantics).
__global__ void k_cmin(const float* __restrict__ bias0, int* __restrict__ cmin) {
    int h = blockIdx.x * blockDim.x + threadIdx.x;
    float b0 = bias0[h];
    int c = (int)(1.0f - b0);
    if (c < 0) c = 0;
    int guard = 0;
    while ((float)c + b0 <= 1.0f && guard++ < 100000) ++c;
    while (c > 0 && (float)(c - 1) + b0 > 1.0f) --c;
    cmin[h] = c;
}

// Row sums of clf_weight (classification for an all-ones z row).
__global__ void k_rowsum(const float* __restrict__ clf, float* __restrict__ R) {
    __shared__ float s[256];
    int l = blockIdx.x;
    float acc = 0.f;
    for (int h = threadIdx.x; h < H; h += 256) acc += clf[(size_t)l * H + h];
    s[threadIdx.x] = acc;
    __syncthreads();
    for (int off = 128; off > 0; off >>= 1) {
        if ((int)threadIdx.x < off) s[threadIdx.x] += s[threadIdx.x + off];
        __syncthreads();
    }
    if (threadIdx.x == 0) R[l] = s[0];
}

// ---------------- main z computation (early-exit popcount GEMM) ----------------

__global__ __launch_bounds__(256) void k_z(const u64* __restrict__ xp,
                                           const u64* __restrict__ wbpw,
                                           const int* __restrict__ cmin,
                                           float* __restrict__ zout,
                                           u64* __restrict__ zp) {
    int wid = (blockIdx.x * 256 + threadIdx.x) >> 6;
    int lane = threadIdx.x & 63;
    int b = wid >> 6;          // H/64 = 64 hblocks per b
    int hb = wid & (HW - 1);
    int h = hb * 64 + lane;
    int cm = cmin[h];
    int cnt = 0;
    const u64* __restrict__ xr = xp + (size_t)b * DW;
    #pragma unroll 1
    for (int w = 0; w < DW; ++w) {
        if (__all(cnt >= cm)) break;       // wave-wide early exit (typ. after 2-4 words)
        if (cnt < cm) {
            u64 a = xr[w];                 // wave-uniform -> scalar load
            u64 wv = wbpw[(size_t)w * H + h]; // coalesced 64x8B
            cnt += (int)__popcll(a & wv);
        }
    }
    int zb = (cnt >= cm) ? 1 : 0;
    zout[(size_t)b * H + h] = zb ? 1.0f : 0.0f;
    u64 m = __ballot(zb);
    if (lane == 0) zp[(size_t)b * HW + hb] = m;
}

// Per-row zero counts of z (no atomics needed).
__global__ void k_nz(const u64* __restrict__ zp, int* __restrict__ nz) {
    int b = blockIdx.x * blockDim.x + threadIdx.x;
    int s = 0;
    for (int w = 0; w < HW; ++w) s += (int)__popcll(zp[(size_t)b * HW + w]);
    nz[b] = H - s;
}

// ---------------- outputs ----------------

// classification[b][l]: fast path = rowsum(clf); fallback = exact masked sum.
__global__ void k_cls(const u64* __restrict__ zp, const float* __restrict__ R,
                      const float* __restrict__ clf, const int* __restrict__ nz,
                      float* __restrict__ out1) {
    int b = blockIdx.x;
    int l = threadIdx.x;  // 128 threads
    if (nz[b] == 0) {
        out1[(size_t)b * L + l] = R[l];
        return;
    }
    float acc = 0.f;
    for (int wh = 0; wh < HW; ++wh) {
        u64 m = zp[(size_t)b * HW + wh];
        while (m) {
            int j = __ffsll(m) - 1;
            acc += clf[(size_t)l * H + wh * 64 + j];
            m &= m - 1;
        }
    }
    out1[(size_t)b * L + l] = acc;
}

// output[b][d]: fast path = broadcast precomputed row; fallback = exact popcount recon.
__global__ __launch_bounds__(256) void k_out(const float4* __restrict__ base4,
                                             const int* __restrict__ nz,
                                             const u64* __restrict__ zp,
                                             const u64* __restrict__ wbtp,
                                             const float* __restrict__ bias3,
                                             float* __restrict__ out0) {
    int t = blockIdx.x * 256 + threadIdx.x;  // one float4 per thread
    int idx = t * 4;
    int b = idx >> 13;          // D = 8192; 1024 floats per block => b block-uniform
    int d = idx & (D - 1);
    if (nz[b] == 0) {
        ((float4*)out0)[t] = base4[d >> 2];
    } else {
        const u64* __restrict__ zr = zp + (size_t)b * HW;
        for (int k = 0; k < 4; ++k) {
            int dd = d + k;
            int s = 0;
            for (int w = 0; w < HW; ++w) s += (int)__popcll(zr[w] & wbtp[(size_t)dd * HW + w]);
            out0[(size_t)idx + k] = ((float)s + bias3[dd] > 1.0f) ? 1.0f : 0.0f;
        }
    }
}

// ---------------- launch ----------------

extern "C" void kernel_launch(void* const* d_in, const int* in_sizes, int n_in,
                              void* d_out, int out_size, void* d_ws, size_t ws_size,
                              hipStream_t stream) {
    const float* x   = (const float*)d_in[0];
    const float* ew  = (const float*)d_in[1];
    const float* b0  = (const float*)d_in[2];
    const float* b3  = (const float*)d_in[3];
    const float* clf = (const float*)d_in[4];

    float* out0 = (float*)d_out;                 // [B][D]
    float* out1 = out0 + (size_t)B * D;          // [B][L]
    float* zout = out1 + (size_t)B * L;          // [B][H]

    char* ws = (char*)d_ws;
    u64* xp    = (u64*)(ws);                         // 4 MB
    u64* wbpw  = (u64*)(ws + (4ull << 20));          // 4 MB
    u64* wbtp  = (u64*)(ws + (8ull << 20));          // 4 MB
    u64* zp    = (u64*)(ws + (12ull << 20));         // 2 MB
    float* base = (float*)(ws + 14680064ull);        // 32 KB
    float* R    = (float*)(ws + 14712832ull);        // 512 B
    int* cmin   = (int*)(ws + 14713344ull);          // 16 KB
    int* nz     = (int*)(ws + 14729728ull);          // 16 KB

    k_pack_x<<<(B * D) / 256, 256, 0, stream>>>(x, xp);
    k_pack_wb<<<(H * D) / 256, 256, 0, stream>>>(ew, wbpw);
    k_build_wbt<<<(DW * HW * 64) / 256, 256, 0, stream>>>(wbpw, wbtp);
    k_base<<<D / 256, 256, 0, stream>>>(wbtp, b3, base);
    k_cmin<<<H / 256, 256, 0, stream>>>(b0, cmin);
    k_rowsum<<<L, 256, 0, stream>>>(clf, R);
    k_z<<<(B * HW * 64) / 256, 256, 0, stream>>>(xp, wbpw, cmin, zout, zp);
    k_nz<<<B / 256, 256, 0, stream>>>(zp, nz);
    k_cls<<<B, L, 0, stream>>>(zp, R, clf, nz, out1);
    k_out<<<(B * D / 4) / 256, 256, 0, stream>>>((const float4*)base, nz, zp, wbtp, b3, out0);
}

// Round 2
// 469.732 us; speedup vs baseline: 1.1143x; 1.1143x over previous
//
#include <hip/hip_runtime.h>
#include <cstdint>

typedef unsigned long long u64;

constexpr int B = 4096;
constexpr int D = 8192;
constexpr int H = 4096;
constexpr int L = 128;
constexpr int DW = D / 64;   // 128 u64 words along d
constexpr int HW = H / 64;   // 64 u64 words along h

// ---------------- fused packing kernel ----------------
// Grid = B + H blocks. Block r < B packs x row r -> xp[r][DW] (row-major).
// Block r >= B packs enc_weight row h=r-B -> wbpw[w][H] (word-major, so k_z's
// per-lane loads over consecutive h are coalesced).
// Each block: 256 threads = 4 waves; wave handles 8 chunks of 256 elements;
// per chunk: 4 coalesced 256B loads + 4 ballots -> 4 packed words.
__global__ __launch_bounds__(256) void k_pack(const float* __restrict__ x,
                                              const float* __restrict__ e,
                                              u64* __restrict__ xp,
                                              u64* __restrict__ wbpw) {
    int r = blockIdx.x;
    int lane = threadIdx.x & 63;
    int wave = threadIdx.x >> 6;
    bool is_x = (r < B);
    const float* row = is_x ? (x + (size_t)r * D) : (e + (size_t)(r - B) * D);
    #pragma unroll 1
    for (int it = 0; it < 8; ++it) {
        int chunk = wave * 8 + it;            // [0,32): 256-element chunk
        int base = chunk * 256;
        u64 m[4];
        #pragma unroll
        for (int k = 0; k < 4; ++k) {
            float v = row[base + k * 64 + lane];   // coalesced 256B per k
            m[k] = __ballot(v > 0.5f);             // bit `lane` of word chunk*4+k
        }
        if (lane == 0) {
            if (is_x) {
                u64* orow = xp + (size_t)r * DW + chunk * 4;
                orow[0] = m[0]; orow[1] = m[1]; orow[2] = m[2]; orow[3] = m[3];
            } else {
                int h = r - B;
                #pragma unroll
                for (int k = 0; k < 4; ++k)
                    wbpw[(size_t)(chunk * 4 + k) * H + h] = m[k];
            }
        }
    }
}

// Bit-transpose wbpw -> wbtp[d][HW] (bit j of word wh = wb[wh*64+j][d]).
__global__ __launch_bounds__(256) void k_build_wbt(const u64* __restrict__ wbpw,
                                                   u64* __restrict__ wbtp) {
    int wid = (blockIdx.x * 256 + threadIdx.x) >> 6; // wave id
    int lane = threadIdx.x & 63;
    int dblock = wid >> 6;    // [0, DW)
    int wh = wid & (HW - 1);  // [0, HW)
    u64 Wj = wbpw[(size_t)dblock * H + wh * 64 + lane];
    u64 myword = 0;
    #pragma unroll 1
    for (int jj = 0; jj < 64; ++jj) {
        u64 m = __ballot((int)((Wj >> jj) & 1ull));
        if (lane == jj) myword = m;
    }
    wbtp[(size_t)(dblock * 64 + lane) * HW + wh] = myword;
}

// ---------------- tiny precompute kernels ----------------

__global__ void k_base(const u64* __restrict__ wbtp, const float* __restrict__ bias3,
                       float* __restrict__ base) {
    int d = blockIdx.x * blockDim.x + threadIdx.x;
    int s = 0;
    for (int w = 0; w < HW; ++w) s += (int)__popcll(wbtp[(size_t)d * HW + w]);
    base[d] = ((float)s + bias3[d] > 1.0f) ? 1.0f : 0.0f;
}

// Minimal integer c with (float)c + bias0[h] > 1.0f (exact fp32 semantics).
__global__ void k_cmin(const float* __restrict__ bias0, int* __restrict__ cmin) {
    int h = blockIdx.x * blockDim.x + threadIdx.x;
    float b0 = bias0[h];
    int c = (int)(1.0f - b0);
    if (c < 0) c = 0;
    int guard = 0;
    while ((float)c + b0 <= 1.0f && guard++ < 100000) ++c;
    while (c > 0 && (float)(c - 1) + b0 > 1.0f) --c;
    cmin[h] = c;
}

__global__ void k_rowsum(const float* __restrict__ clf, float* __restrict__ R) {
    __shared__ float s[256];
    int l = blockIdx.x;
    float acc = 0.f;
    for (int h = threadIdx.x; h < H; h += 256) acc += clf[(size_t)l * H + h];
    s[threadIdx.x] = acc;
    __syncthreads();
    for (int off = 128; off > 0; off >>= 1) {
        if ((int)threadIdx.x < off) s[threadIdx.x] += s[threadIdx.x + off];
        __syncthreads();
    }
    if (threadIdx.x == 0) R[l] = s[0];
}

// ---------------- main z computation (early-exit popcount GEMM) ----------------
// Grid-stride over (b, hb) pairs: 8192 blocks x 4 waves, 8 pairs per wave.
__global__ __launch_bounds__(256) void k_z(const u64* __restrict__ xp,
                                           const u64* __restrict__ wbpw,
                                           const int* __restrict__ cmin,
                                           float* __restrict__ zout,
                                           u64* __restrict__ zp) {
    int wid0 = (blockIdx.x * 256 + threadIdx.x) >> 6;
    int lane = threadIdx.x & 63;
    int nwaves = gridDim.x * 4;
    #pragma unroll 1
    for (int pair = wid0; pair < B * HW; pair += nwaves) {
        int b = pair >> 6;         // HW = 64
        int hb = pair & (HW - 1);
        int h = hb * 64 + lane;
        int cm = cmin[h];
        int cnt = 0;
        const u64* __restrict__ xr = xp + (size_t)b * DW;
        #pragma unroll 1
        for (int w = 0; w < DW; ++w) {
            if (__all(cnt >= cm)) break;   // typ. after 3-4 words
            if (cnt < cm) {
                u64 a = xr[w];
                u64 wv = wbpw[(size_t)w * H + h];  // coalesced 512B
                cnt += (int)__popcll(a & wv);
            }
        }
        int zb = (cnt >= cm) ? 1 : 0;
        zout[(size_t)b * H + h] = zb ? 1.0f : 0.0f;
        u64 m = __ballot(zb);
        if (lane == 0) zp[(size_t)b * HW + hb] = m;
    }
}

// Per-row zero counts of z.
__global__ void k_nz(const u64* __restrict__ zp, int* __restrict__ nz) {
    int b = blockIdx.x * blockDim.x + threadIdx.x;
    int s = 0;
    for (int w = 0; w < HW; ++w) s += (int)__popcll(zp[(size_t)b * HW + w]);
    nz[b] = H - s;
}

// ---------------- outputs ----------------

// classification: fast path = rowsum(clf); fallback = exact masked sum.
// Block = 256 threads handles 2 b-rows.
__global__ __launch_bounds__(256) void k_cls(const u64* __restrict__ zp,
                                             const float* __restrict__ R,
                                             const float* __restrict__ clf,
                                             const int* __restrict__ nz,
                                             float* __restrict__ out1) {
    int b = blockIdx.x * 2 + (threadIdx.x >> 7);
    int l = threadIdx.x & (L - 1);
    if (nz[b] == 0) {
        out1[(size_t)b * L + l] = R[l];
        return;
    }
    float acc = 0.f;
    for (int wh = 0; wh < HW; ++wh) {
        u64 m = zp[(size_t)b * HW + wh];
        while (m) {
            int j = __ffsll(m) - 1;
            acc += clf[(size_t)l * H + wh * 64 + j];
            m &= m - 1;
        }
    }
    out1[(size_t)b * L + l] = acc;
}

// output[b][d]: fast path = broadcast precomputed row (pure 16B stores);
// fallback = exact popcount recon. Grid-stride, 4 float4 per thread.
__global__ __launch_bounds__(256) void k_out(const float4* __restrict__ base4,
                                             const int* __restrict__ nz,
                                             const u64* __restrict__ zp,
                                             const u64* __restrict__ wbtp,
                                             const float* __restrict__ bias3,
                                             float* __restrict__ out0) {
    int nf4 = B * D / 4;
    int stride = gridDim.x * 256;
    #pragma unroll 1
    for (int t = blockIdx.x * 256 + threadIdx.x; t < nf4; t += stride) {
        int idx = t * 4;
        int b = idx >> 13;          // block-uniform (1024-float spans align to rows)
        int d = idx & (D - 1);
        if (nz[b] == 0) {
            ((float4*)out0)[t] = base4[d >> 2];
        } else {
            const u64* __restrict__ zr = zp + (size_t)b * HW;
            for (int k = 0; k < 4; ++k) {
                int dd = d + k;
                int s = 0;
                for (int w = 0; w < HW; ++w)
                    s += (int)__popcll(zr[w] & wbtp[(size_t)dd * HW + w]);
                out0[(size_t)idx + k] = ((float)s + bias3[dd] > 1.0f) ? 1.0f : 0.0f;
            }
        }
    }
}

// ---------------- launch ----------------

extern "C" void kernel_launch(void* const* d_in, const int* in_sizes, int n_in,
                              void* d_out, int out_size, void* d_ws, size_t ws_size,
                              hipStream_t stream) {
    const float* x   = (const float*)d_in[0];
    const float* ew  = (const float*)d_in[1];
    const float* b0  = (const float*)d_in[2];
    const float* b3  = (const float*)d_in[3];
    const float* clf = (const float*)d_in[4];

    float* out0 = (float*)d_out;                 // [B][D]
    float* out1 = out0 + (size_t)B * D;          // [B][L]
    float* zout = out1 + (size_t)B * L;          // [B][H]

    char* ws = (char*)d_ws;
    u64* xp    = (u64*)(ws);                         // 4 MB
    u64* wbpw  = (u64*)(ws + (4ull << 20));          // 4 MB
    u64* wbtp  = (u64*)(ws + (8ull << 20));          // 4 MB
    u64* zp    = (u64*)(ws + (12ull << 20));         // 2 MB
    float* base = (float*)(ws + 14680064ull);        // 32 KB
    float* R    = (float*)(ws + 14712832ull);        // 512 B
    int* cmin   = (int*)(ws + 14713344ull);          // 16 KB
    int* nz     = (int*)(ws + 14729728ull);          // 16 KB

    k_pack<<<B + H, 256, 0, stream>>>(x, ew, xp, wbpw);
    k_build_wbt<<<(DW * HW * 64) / 256, 256, 0, stream>>>(wbpw, wbtp);
    k_base<<<D / 256, 256, 0, stream>>>(wbtp, b3, base);
    k_cmin<<<H / 256, 256, 0, stream>>>(b0, cmin);
    k_rowsum<<<L, 256, 0, stream>>>(clf, R);
    k_z<<<8192, 256, 0, stream>>>(xp, wbpw, cmin, zout, zp);
    k_nz<<<B / 256, 256, 0, stream>>>(zp, nz);
    k_cls<<<B / 2, 256, 0, stream>>>(zp, R, clf, nz, out1);
    k_out<<<8192, 256, 0, stream>>>((const float4*)base, nz, zp, wbtp, b3, out0);
}